// Round 7
// baseline (107.696 us; speedup 1.0000x reference)
//
#include <hip/hip_runtime.h>

// Submanifold sparse 3D conv — v7: v5 skeleton (TR=32, 4-wave blocks) +
// depth-2 gather pipeline + bijective XCD swizzle + center folded into tab.
// Per phase (27 total): prefetch W(it+1)->regs, gather A(it+2), tab(it+5);
// compute item it (8 swizzled ds_read_b128 + 16 MFMA); ds_write W(it+1);
// raw s_barrier with lgkmcnt-only drain (vmem prefetches stay in flight).
//
// Map identity (verified R1-R5): out[imap[m,p]] += feats[omap[m,p]] @ kernel[26-kk(m)]
// tab[27][nt][32]: maps 0..25 = scattered omap (empties = N -> zero row);
// map 26 = identity (center). fb has N+1 rows; row N = 0.

#define CIN 64
#define COUT 64
#define TR 32
#define NOFF 26

typedef short bf16x8 __attribute__((ext_vector_type(8)));
typedef unsigned short ushort8 __attribute__((ext_vector_type(8)));
typedef float f32x4 __attribute__((ext_vector_type(4)));

__device__ inline unsigned short bfbits(float f) {
    unsigned u = __builtin_bit_cast(unsigned, f);
    u += 0x7fffu + ((u >> 16) & 1u);          // RNE
    return (unsigned short)(u >> 16);
}

__device__ inline int kk_of_item(int i) {
    return (i >= 26) ? 13 : 26 - (i < 13 ? i : i + 1);
}

// ---------- prepass 1: feats f32 -> bf16 ----------------------------------
__global__ __launch_bounds__(256) void prep_feats(const float* __restrict__ f,
                                                  unsigned short* __restrict__ fb,
                                                  int n) {
    const int i8 = (blockIdx.x * 256 + threadIdx.x) * 8;
    if (i8 >= n) return;
    const float4 v0 = *(const float4*)(f + i8);
    const float4 v1 = *(const float4*)(f + i8 + 4);
    union { unsigned short u[8]; bf16x8 v; } r;
    r.u[0] = bfbits(v0.x); r.u[1] = bfbits(v0.y);
    r.u[2] = bfbits(v0.z); r.u[3] = bfbits(v0.w);
    r.u[4] = bfbits(v1.x); r.u[5] = bfbits(v1.y);
    r.u[6] = bfbits(v1.z); r.u[7] = bfbits(v1.w);
    *(bf16x8*)(fb + i8) = r.v;
}

// ---------- prepass 2: W [27][c][o] f32 -> Wt [27][o][c] bf16, PRE-SWIZZLED
__global__ __launch_bounds__(256) void prep_wt(const float* __restrict__ W,
                                               unsigned short* __restrict__ Wt) {
    const int k = blockIdx.x;
    for (int idx = threadIdx.x; idx < CIN * COUT; idx += 256) {
        const int c = idx >> 6, o = idx & 63;
        const int q = c >> 3, e = c & 7;
        Wt[((k * 64 + o) * 64) + (((q ^ (o & 7)) << 3) + e)] =
            bfbits(W[(k * 64 + c) * 64 + o]);
    }
}

// ---------- prepass 3: tab init (N everywhere; identity on map 26) --------
__global__ __launch_bounds__(256) void prep_tab_init(int* __restrict__ tab,
                                                     int nt, int N) {
    const size_t i4 = ((size_t)blockIdx.x * 256 + threadIdx.x) * 4;
    const size_t total = (size_t)27 * nt * TR;
    if (i4 >= total) return;
    const size_t mstep = (size_t)nt * TR;
    int4 v;
    int* vp = (int*)&v;
#pragma unroll
    for (int e = 0; e < 4; ++e) {
        const size_t l = i4 + e;
        const int m = (int)(l / mstep);
        const int r = (int)(l - (size_t)m * mstep);    // row within map
        vp[e] = (m == 26 && r < N) ? r : N;
    }
    *(int4*)(tab + i4) = v;
}

__global__ __launch_bounds__(256) void prep_tab(const int* __restrict__ imap,
                                                const int* __restrict__ omap,
                                                int P, int nt,
                                                int* __restrict__ tab) {
    const int p = blockIdx.x * 256 + threadIdx.x;
    const int m = blockIdx.y;
    if (p >= P) return;
    const int iv = imap[(size_t)m * P + p];
    if (iv < 0) return;
    tab[((size_t)m * nt + (iv >> 5)) * TR + (iv & 31)] = omap[(size_t)m * P + p];
}

// ---------- main ----------------------------------------------------------
__global__ __launch_bounds__(256, 4) void spconv_v7(
    const unsigned short* __restrict__ fb,   // feats bf16 [N+1][64], row N = 0
    const unsigned short* __restrict__ wt,   // [27][64][64] bf16, pre-swizzled
    const int* __restrict__ tab,             // [27][nt][32]
    float* __restrict__ out, int N, int nt, int nwg)
{
    __shared__ unsigned short wbuf[2][4096]; // 2 x 8KB double buffer

    const int tid = threadIdx.x, w = tid >> 6, lane = tid & 63;
    const int col = lane & 15, grp = lane >> 4;

    // bijective XCD swizzle (m204): consecutive swizzled ids share an XCD
    const int orig = blockIdx.x;
    const int q = nwg >> 3, r8 = nwg & 7;
    const int xcd = orig & 7, k = orig >> 3;
    const int sb = (xcd < r8 ? xcd * (q + 1) : r8 * (q + 1) + (xcd - r8) * q) + k;

    const int t = sb * 4 + w;                // this wave's 32-row tile
    const int tt = (t < nt) ? t : (nt - 1);
    const int r0 = t * TR;
    const size_t tstep = (size_t)nt * TR;
    const int* tb = tab + (size_t)tt * TR + col;

#define TAB(j, s) tb[(size_t)((j) < 27 ? (j) : 26) * tstep + (s) * 16]

    // --- prologue: tab + gather pipelines ---
    int sv1[2], sv2[2], tvA[2], tvB[2];
    bf16x8 a0[2][2], a1[2][2], a2[2][2];
#pragma unroll
    for (int s = 0; s < 2; ++s) {
        const int sv0 = TAB(0, s);
        sv1[s] = TAB(1, s);
        sv2[s] = TAB(2, s);
        tvA[s] = TAB(3, s);
        tvB[s] = TAB(4, s);
        const bf16x8* fp = (const bf16x8*)(fb + (size_t)sv0 * 64 + grp * 8);
        a0[s][0] = fp[0];
        a0[s][1] = fp[4];
        const bf16x8* fq = (const bf16x8*)(fb + (size_t)sv1[s] * 64 + grp * 8);
        a1[s][0] = fq[0];
        a1[s][1] = fq[4];
    }

    // stage W(item 0): linear copy (source pre-swizzled), 32B/lane
    {
        const unsigned short* wk = wt + kk_of_item(0) * 4096;
        const ushort8 wl0 = *(const ushort8*)(wk + tid * 8);
        const ushort8 wl1 = *(const ushort8*)(wk + 2048 + tid * 8);
        *(ushort8*)(&wbuf[0][tid * 8]) = wl0;
        *(ushort8*)(&wbuf[0][2048 + tid * 8]) = wl1;
    }
    asm volatile("s_waitcnt lgkmcnt(0)" ::: "memory");
    __builtin_amdgcn_s_barrier();

    f32x4 acc[2][4];
#pragma unroll
    for (int s = 0; s < 2; ++s)
#pragma unroll
        for (int ot = 0; ot < 4; ++ot) acc[s][ot] = {0.f, 0.f, 0.f, 0.f};

    for (int it = 0; it < 27; ++it) {
        // (1) next item's W -> regs (L2-hot)
        const unsigned short* wkn = wt + kk_of_item(it + 1) * 4096;
        const ushort8 wl0 = *(const ushort8*)(wkn + tid * 8);
        const ushort8 wl1 = *(const ushort8*)(wkn + 2048 + tid * 8);

        // (2) gather item it+2 (2 phases of latency cover)
#pragma unroll
        for (int s = 0; s < 2; ++s) {
            const bf16x8* fp = (const bf16x8*)(fb + (size_t)sv2[s] * 64 + grp * 8);
            a2[s][0] = fp[0];
            a2[s][1] = fp[4];
        }

        // (3) tab pipeline: consume tvA (item it+3), issue it+5
        int svn[2];
#pragma unroll
        for (int s = 0; s < 2; ++s) {
            svn[s] = tvA[s];
            tvA[s] = tvB[s];
            tvB[s] = TAB(it + 5, s);
        }

        // (4) compute item it: 8 swizzled ds_read_b128 + 16 MFMA
        const unsigned short* cb = wbuf[it & 1];
        __builtin_amdgcn_s_setprio(1);
#pragma unroll
        for (int ot = 0; ot < 4; ++ot) {
            const int o = ot * 16 + col;
            const bf16x8 b0 = *(const bf16x8*)(cb + o * 64 + ((grp ^ (col & 7)) << 3));
            const bf16x8 b1 = *(const bf16x8*)(cb + o * 64 + (((4 + grp) ^ (col & 7)) << 3));
#pragma unroll
            for (int s = 0; s < 2; ++s) {
                acc[s][ot] = __builtin_amdgcn_mfma_f32_16x16x32_bf16(a0[s][0], b0, acc[s][ot], 0, 0, 0);
                acc[s][ot] = __builtin_amdgcn_mfma_f32_16x16x32_bf16(a0[s][1], b1, acc[s][ot], 0, 0, 0);
            }
        }
        __builtin_amdgcn_s_setprio(0);

        // (5) stage next W into the other buffer
        unsigned short* nb = wbuf[(it + 1) & 1];
        *(ushort8*)(&nb[tid * 8]) = wl0;
        *(ushort8*)(&nb[2048 + tid * 8]) = wl1;

        // (6) raw barrier: drain LDS only; vmem prefetches stay in flight
        asm volatile("s_waitcnt lgkmcnt(0)" ::: "memory");
        __builtin_amdgcn_s_barrier();

        // (7) rotate pipelines
#pragma unroll
        for (int s = 0; s < 2; ++s) {
            a0[s][0] = a1[s][0]; a0[s][1] = a1[s][1];
            a1[s][0] = a2[s][0]; a1[s][1] = a2[s][1];
            sv2[s] = svn[s];
        }
    }

    // --- write-out ---
#pragma unroll
    for (int s = 0; s < 2; ++s)
#pragma unroll
        for (int ot = 0; ot < 4; ++ot) {
            const f32x4 cv = acc[s][ot];
#pragma unroll
            for (int reg = 0; reg < 4; ++reg) {
                const int rr = r0 + s * 16 + grp * 4 + reg;
                if (rr < N) out[(size_t)rr * 64 + ot * 16 + col] = cv[reg];
            }
        }
#undef TAB
}

// ---------- fallback (fp32 + atomics, round-0) ----------------------------
template <int MODE>
__global__ __launch_bounds__(256) void spconv_fb(
    const float* __restrict__ feats, const float* __restrict__ W,
    const int* __restrict__ imap, const int* __restrict__ omap,
    float* __restrict__ out, int npairs)
{
    __shared__ float4 wt4[16 * 64];
    const int tid = threadIdx.x, koff = blockIdx.y;
    const float* Wk;
    const int* im = nullptr; const int* om = nullptr;
    if (MODE == 0) Wk = W + 13 * (CIN * COUT);
    else {
        const int kk = (koff < 13) ? koff : koff + 1;
        Wk = W + (size_t)kk * (CIN * COUT);
        im = imap + (size_t)koff * npairs; om = omap + (size_t)koff * npairs;
    }
    float* wts = (float*)wt4;
    for (int idx = tid; idx < CIN * COUT; idx += 256) {
        const int c = idx >> 6, o = idx & 63;
        wts[((c >> 2) * 64 + o) * 4 + (c & 3)] = Wk[idx];
    }
    __syncthreads();
    const int o = tid & 63, w = tid >> 6;
    const int base = blockIdx.x * 256 + w * 64;
    const float4* f4p = (const float4*)feats;
    for (int n = 0; n < 64; ++n) {
        const int p = base + n;
        if (p >= npairs) break;
        int i, j;
        if (MODE == 0) { i = p; j = p; }
        else { i = im[p]; if (i < 0) continue; j = om[p]; }
        i = __builtin_amdgcn_readfirstlane(i);
        float a = 0.f;
#pragma unroll
        for (int c4 = 0; c4 < 16; ++c4) {
            const float4 f = f4p[(size_t)i * 16 + c4];
            const float4 wv = wt4[c4 * 64 + o];
            a += f.x * wv.x + f.y * wv.y + f.z * wv.z + f.w * wv.w;
        }
        if (MODE == 0) out[(size_t)j * COUT + o] = a;
        else atomicAdd(&out[(size_t)j * COUT + o], a);
    }
}

extern "C" void kernel_launch(void* const* d_in, const int* in_sizes, int n_in,
                              void* d_out, int out_size, void* d_ws, size_t ws_size,
                              hipStream_t stream) {
    const float* feats = (const float*)d_in[0];
    const float* W     = (const float*)d_in[1];
    const int* imap    = (const int*)d_in[2];
    const int* omap    = (const int*)d_in[3];
    float* out         = (float*)d_out;

    const int N = in_sizes[0] / CIN;
    const int P = in_sizes[2] / NOFF;
    const int nt = (N + TR - 1) / TR;                       // 32-row tiles (6250)

    const size_t fb_bytes  = (size_t)(N + 1) * 64 * sizeof(unsigned short);
    const size_t wt_bytes  = 27 * 64 * 64 * sizeof(unsigned short);
    const size_t tab_bytes = (size_t)27 * nt * TR * sizeof(int);

    if (ws_size < fb_bytes + wt_bytes + tab_bytes) {
        dim3 blk(256);
        dim3 gc((N + 255) / 256, 1);
        spconv_fb<0><<<gc, blk, 0, stream>>>(feats, W, nullptr, nullptr, out, N);
        dim3 go((P + 255) / 256, NOFF);
        spconv_fb<1><<<go, blk, 0, stream>>>(feats, W, imap, omap, out, P);
        return;
    }

    unsigned short* fbp = (unsigned short*)d_ws;
    unsigned short* Wt  = (unsigned short*)((char*)d_ws + fb_bytes);
    int* tab            = (int*)((char*)d_ws + fb_bytes + wt_bytes);

    const int nf = N * 64;
    prep_feats<<<(nf / 8 + 255) / 256, 256, 0, stream>>>(feats, fbp, nf);
    hipMemsetAsync(fbp + (size_t)N * 64, 0, 128, stream);   // zero row N
    prep_wt<<<27, 256, 0, stream>>>(W, Wt);
    const size_t tot4 = (size_t)27 * nt * TR / 4;
    prep_tab_init<<<(int)((tot4 + 255) / 256), 256, 0, stream>>>(tab, nt, N);
    prep_tab<<<dim3((P + 255) / 256, NOFF), 256, 0, stream>>>(imap, omap, P, nt, tab);

    const int nwg = (nt + 3) / 4;                           // 1563
    spconv_v7<<<nwg, 256, 0, stream>>>(fbp, Wt, tab, out, N, nt, nwg);
}

// Round 8
// 98.126 us; speedup vs baseline: 1.0975x; 1.0975x over previous
//
#include <hip/hip_runtime.h>

// Submanifold sparse 3D conv — v8: fully-unrolled 27-phase software pipeline.
// Per phase: load W(it+2)->regs; gather A(it+2); tab(it+4); ds_write W(it+1)
// (regs loaded a full phase ago -> no vmcnt stall); compute item it
// (8 swizzled ds_read_b128 + 16 MFMA); lgkmcnt(0)+s_barrier.
// Full unroll => all pipeline arrays statically indexed (no rotate movs).
//
// Map identity (verified R1-R6): out[imap[m,p]] += feats[omap[m,p]] @ kernel[26-kk(m)]
// tab[27][nt][32]: maps 0..25 scattered omap (empties = N -> zero row);
// map 26 = identity (center). fb has N+1 rows; row N = 0. W pre-swizzled.

#define CIN 64
#define COUT 64
#define TR 32
#define NOFF 26

typedef short bf16x8 __attribute__((ext_vector_type(8)));
typedef unsigned short ushort8 __attribute__((ext_vector_type(8)));
typedef float f32x4 __attribute__((ext_vector_type(4)));

__device__ inline unsigned short bfbits(float f) {
    unsigned u = __builtin_bit_cast(unsigned, f);
    u += 0x7fffu + ((u >> 16) & 1u);          // RNE
    return (unsigned short)(u >> 16);
}

__device__ inline constexpr int kk_of_item(int i) {
    return (i >= 26) ? 13 : 26 - (i < 13 ? i : i + 1);
}

// ---------- prepass 1: feats f32 -> bf16 ----------------------------------
__global__ __launch_bounds__(256) void prep_feats(const float* __restrict__ f,
                                                  unsigned short* __restrict__ fb,
                                                  int n) {
    const int i8 = (blockIdx.x * 256 + threadIdx.x) * 8;
    if (i8 >= n) return;
    const float4 v0 = *(const float4*)(f + i8);
    const float4 v1 = *(const float4*)(f + i8 + 4);
    union { unsigned short u[8]; bf16x8 v; } r;
    r.u[0] = bfbits(v0.x); r.u[1] = bfbits(v0.y);
    r.u[2] = bfbits(v0.z); r.u[3] = bfbits(v0.w);
    r.u[4] = bfbits(v1.x); r.u[5] = bfbits(v1.y);
    r.u[6] = bfbits(v1.z); r.u[7] = bfbits(v1.w);
    *(bf16x8*)(fb + i8) = r.v;
}

// ---------- prepass 2: W [27][c][o] f32 -> Wt [27][o][c] bf16, PRE-SWIZZLED
__global__ __launch_bounds__(256) void prep_wt(const float* __restrict__ W,
                                               unsigned short* __restrict__ Wt) {
    const int k = blockIdx.x;
    for (int idx = threadIdx.x; idx < CIN * COUT; idx += 256) {
        const int c = idx >> 6, o = idx & 63;
        const int q = c >> 3, e = c & 7;
        Wt[((k * 64 + o) * 64) + (((q ^ (o & 7)) << 3) + e)] =
            bfbits(W[(k * 64 + c) * 64 + o]);
    }
}

// ---------- prepass 3: tab init (N everywhere; identity on map 26) --------
__global__ __launch_bounds__(256) void prep_tab_init(int* __restrict__ tab,
                                                     int nt, int N) {
    const size_t i4 = ((size_t)blockIdx.x * 256 + threadIdx.x) * 4;
    const size_t total = (size_t)27 * nt * TR;
    if (i4 >= total) return;
    const size_t mstep = (size_t)nt * TR;
    int4 v;
    int* vp = (int*)&v;
#pragma unroll
    for (int e = 0; e < 4; ++e) {
        const size_t l = i4 + e;
        const int m = (int)(l / mstep);
        const int r = (int)(l - (size_t)m * mstep);
        vp[e] = (m == 26 && r < N) ? r : N;
    }
    *(int4*)(tab + i4) = v;
}

__global__ __launch_bounds__(256) void prep_tab(const int* __restrict__ imap,
                                                const int* __restrict__ omap,
                                                int P, int nt,
                                                int* __restrict__ tab) {
    const int p = blockIdx.x * 256 + threadIdx.x;
    const int m = blockIdx.y;
    if (p >= P) return;
    const int iv = imap[(size_t)m * P + p];
    if (iv < 0) return;
    tab[((size_t)m * nt + (iv >> 5)) * TR + (iv & 31)] = omap[(size_t)m * P + p];
}

// ---------- main ----------------------------------------------------------
__global__ __launch_bounds__(256, 4) void spconv_v8(
    const unsigned short* __restrict__ fb,   // feats bf16 [N+1][64], row N = 0
    const unsigned short* __restrict__ wt,   // [27][64][64] bf16, pre-swizzled
    const int* __restrict__ tab,             // [27][nt][32]
    float* __restrict__ out, int N, int nt, int nwg)
{
    __shared__ unsigned short wbuf[2][4096]; // 2 x 8KB double buffer

    const int tid = threadIdx.x, w = tid >> 6, lane = tid & 63;
    const int col = lane & 15, grp = lane >> 4;

    // bijective XCD swizzle (m204)
    const int orig = blockIdx.x;
    const int q = nwg >> 3, r8 = nwg & 7;
    const int xcd = orig & 7, kb = orig >> 3;
    const int sb = (xcd < r8 ? xcd * (q + 1) : r8 * (q + 1) + (xcd - r8) * q) + kb;

    const int t = sb * 4 + w;                // this wave's 32-row tile
    const int tt = (t < nt) ? t : (nt - 1);
    const int r0 = t * TR;
    const size_t tstep = (size_t)nt * TR;
    const int* tb = tab + (size_t)tt * TR + col;

    // pipeline state — ALL statically indexed (full unroll => registers)
    int svr[27][2];
    bf16x8 af[27][2][2];
    ushort8 wr[27][2];

    // --- prologue ---
#pragma unroll
    for (int j = 0; j < 4; ++j)
#pragma unroll
        for (int s = 0; s < 2; ++s) svr[j][s] = tb[(size_t)j * tstep + s * 16];

#pragma unroll
    for (int j = 0; j < 2; ++j)
#pragma unroll
        for (int s = 0; s < 2; ++s) {
            const bf16x8* fp = (const bf16x8*)(fb + (size_t)svr[j][s] * 64 + grp * 8);
            af[j][s][0] = fp[0];
            af[j][s][1] = fp[4];
        }

    {   // W0 -> buf0 (via temp regs), W1 -> wr[1]
        const unsigned short* wk0 = wt + kk_of_item(0) * 4096;
        const ushort8 t0 = *(const ushort8*)(wk0 + tid * 8);
        const ushort8 t1 = *(const ushort8*)(wk0 + 2048 + tid * 8);
        const unsigned short* wk1 = wt + kk_of_item(1) * 4096;
        wr[1][0] = *(const ushort8*)(wk1 + tid * 8);
        wr[1][1] = *(const ushort8*)(wk1 + 2048 + tid * 8);
        *(ushort8*)(&wbuf[0][tid * 8]) = t0;          // compiler inserts vmcnt wait
        *(ushort8*)(&wbuf[0][2048 + tid * 8]) = t1;
    }
    asm volatile("s_waitcnt lgkmcnt(0)" ::: "memory");
    __builtin_amdgcn_s_barrier();

    f32x4 acc[2][4];
#pragma unroll
    for (int s = 0; s < 2; ++s)
#pragma unroll
        for (int ot = 0; ot < 4; ++ot) acc[s][ot] = {0.f, 0.f, 0.f, 0.f};

    // --- 27 fully-unrolled phases ---
#pragma unroll
    for (int it = 0; it < 27; ++it) {
        // (1) W(it+2) -> regs (consumed by ds_write next phase: no vmcnt stall)
        if (it + 2 <= 26) {
            const unsigned short* wk = wt + kk_of_item(it + 2) * 4096;
            wr[it + 2][0] = *(const ushort8*)(wk + tid * 8);
            wr[it + 2][1] = *(const ushort8*)(wk + 2048 + tid * 8);
        }
        // (2) gather A(it+2) — 2 phases of latency cover
        if (it + 2 <= 26) {
#pragma unroll
            for (int s = 0; s < 2; ++s) {
                const bf16x8* fp = (const bf16x8*)(fb + (size_t)svr[it + 2][s] * 64 + grp * 8);
                af[it + 2][s][0] = fp[0];
                af[it + 2][s][1] = fp[4];
            }
        }
        // (3) tab load for item it+4 (2 phases before its gather)
        if (it + 4 <= 26) {
#pragma unroll
            for (int s = 0; s < 2; ++s)
                svr[it + 4][s] = tb[(size_t)(it + 4) * tstep + s * 16];
        }
        // (4) ds_write W(it+1) into the other buffer (regs loaded last phase)
        if (it + 1 <= 26) {
            unsigned short* nb = wbuf[(it + 1) & 1];
            *(ushort8*)(&nb[tid * 8]) = wr[it + 1][0];
            *(ushort8*)(&nb[2048 + tid * 8]) = wr[it + 1][1];
        }
        // (5) compute item it: 8 swizzled ds_read_b128 + 16 MFMA
        const unsigned short* cb = wbuf[it & 1];
        __builtin_amdgcn_s_setprio(1);
#pragma unroll
        for (int ot = 0; ot < 4; ++ot) {
            const int o = ot * 16 + col;
            const bf16x8 b0 = *(const bf16x8*)(cb + o * 64 + ((grp ^ (col & 7)) << 3));
            const bf16x8 b1 = *(const bf16x8*)(cb + o * 64 + (((4 + grp) ^ (col & 7)) << 3));
#pragma unroll
            for (int s = 0; s < 2; ++s) {
                acc[s][ot] = __builtin_amdgcn_mfma_f32_16x16x32_bf16(af[it][s][0], b0, acc[s][ot], 0, 0, 0);
                acc[s][ot] = __builtin_amdgcn_mfma_f32_16x16x32_bf16(af[it][s][1], b1, acc[s][ot], 0, 0, 0);
            }
        }
        __builtin_amdgcn_s_setprio(0);
        // (6) drain LDS ops only; vmem prefetches stay in flight
        if (it < 26) {
            asm volatile("s_waitcnt lgkmcnt(0)" ::: "memory");
            __builtin_amdgcn_s_barrier();
        }
    }

    // --- write-out ---
#pragma unroll
    for (int s = 0; s < 2; ++s)
#pragma unroll
        for (int ot = 0; ot < 4; ++ot) {
            const f32x4 cv = acc[s][ot];
#pragma unroll
            for (int reg = 0; reg < 4; ++reg) {
                const int rr = r0 + s * 16 + grp * 4 + reg;
                if (rr < N) out[(size_t)rr * 64 + ot * 16 + col] = cv[reg];
            }
        }
}

// ---------- fallback (fp32 + atomics, round-0) ----------------------------
template <int MODE>
__global__ __launch_bounds__(256) void spconv_fb(
    const float* __restrict__ feats, const float* __restrict__ W,
    const int* __restrict__ imap, const int* __restrict__ omap,
    float* __restrict__ out, int npairs)
{
    __shared__ float4 wt4[16 * 64];
    const int tid = threadIdx.x, koff = blockIdx.y;
    const float* Wk;
    const int* im = nullptr; const int* om = nullptr;
    if (MODE == 0) Wk = W + 13 * (CIN * COUT);
    else {
        const int kk = (koff < 13) ? koff : koff + 1;
        Wk = W + (size_t)kk * (CIN * COUT);
        im = imap + (size_t)koff * npairs; om = omap + (size_t)koff * npairs;
    }
    float* wts = (float*)wt4;
    for (int idx = tid; idx < CIN * COUT; idx += 256) {
        const int c = idx >> 6, o = idx & 63;
        wts[((c >> 2) * 64 + o) * 4 + (c & 3)] = Wk[idx];
    }
    __syncthreads();
    const int o = tid & 63, w = tid >> 6;
    const int base = blockIdx.x * 256 + w * 64;
    const float4* f4p = (const float4*)feats;
    for (int n = 0; n < 64; ++n) {
        const int p = base + n;
        if (p >= npairs) break;
        int i, j;
        if (MODE == 0) { i = p; j = p; }
        else { i = im[p]; if (i < 0) continue; j = om[p]; }
        i = __builtin_amdgcn_readfirstlane(i);
        float a = 0.f;
#pragma unroll
        for (int c4 = 0; c4 < 16; ++c4) {
            const float4 f = f4p[(size_t)i * 16 + c4];
            const float4 wv = wt4[c4 * 64 + o];
            a += f.x * wv.x + f.y * wv.y + f.z * wv.z + f.w * wv.w;
        }
        if (MODE == 0) out[(size_t)j * COUT + o] = a;
        else atomicAdd(&out[(size_t)j * COUT + o], a);
    }
}

extern "C" void kernel_launch(void* const* d_in, const int* in_sizes, int n_in,
                              void* d_out, int out_size, void* d_ws, size_t ws_size,
                              hipStream_t stream) {
    const float* feats = (const float*)d_in[0];
    const float* W     = (const float*)d_in[1];
    const int* imap    = (const int*)d_in[2];
    const int* omap    = (const int*)d_in[3];
    float* out         = (float*)d_out;

    const int N = in_sizes[0] / CIN;
    const int P = in_sizes[2] / NOFF;
    const int nt = (N + TR - 1) / TR;                       // 32-row tiles (6250)

    const size_t fb_bytes  = (size_t)(N + 1) * 64 * sizeof(unsigned short);
    const size_t wt_bytes  = 27 * 64 * 64 * sizeof(unsigned short);
    const size_t tab_bytes = (size_t)27 * nt * TR * sizeof(int);

    if (ws_size < fb_bytes + wt_bytes + tab_bytes) {
        dim3 blk(256);
        dim3 gc((N + 255) / 256, 1);
        spconv_fb<0><<<gc, blk, 0, stream>>>(feats, W, nullptr, nullptr, out, N);
        dim3 go((P + 255) / 256, NOFF);
        spconv_fb<1><<<go, blk, 0, stream>>>(feats, W, imap, omap, out, P);
        return;
    }

    unsigned short* fbp = (unsigned short*)d_ws;
    unsigned short* Wt  = (unsigned short*)((char*)d_ws + fb_bytes);
    int* tab            = (int*)((char*)d_ws + fb_bytes + wt_bytes);

    const int nf = N * 64;
    prep_feats<<<(nf / 8 + 255) / 256, 256, 0, stream>>>(feats, fbp, nf);
    hipMemsetAsync(fbp + (size_t)N * 64, 0, 128, stream);   // zero row N
    prep_wt<<<27, 256, 0, stream>>>(W, Wt);
    const size_t tot4 = (size_t)27 * nt * TR / 4;
    prep_tab_init<<<(int)((tot4 + 255) / 256), 256, 0, stream>>>(tab, nt, N);
    prep_tab<<<dim3((P + 255) / 256, NOFF), 256, 0, stream>>>(imap, omap, P, nt, tab);

    const int nwg = (nt + 3) / 4;                           // 1563
    spconv_v8<<<nwg, 256, 0, stream>>>(fbp, Wt, tab, out, N, nt, nwg);
}